// Round 9
// baseline (172.725 us; speedup 1.0000x reference)
//
#include <hip/hip_runtime.h>
#include <cstddef>

// Problem constants
constexpr int T_STEPS = 128;
constexpr int BATCH   = 64;
constexpr int N_IN    = 1024;
constexpr int N_OUT   = 1024;
constexpr int M_TOTAL = T_STEPS * BATCH;     // 8192 GEMM rows (m = t*64 + b)
constexpr int NEURONS = BATCH * N_OUT;       // 65536
constexpr int OUT_HALF = T_STEPS * NEURONS;  // 8388608 floats per output tensor

// Exact-arithmetic scheme (unchanged): q = rint(W * 2^34), 4 balanced radix-256
// i8 digits; i32 MFMA accumulation exact; fp64 recombine exact (< 2^42);
// cur = q_sum * 2^-34 exact. Bit-identical outputs vs rounds 3-7.
constexpr double W_SCALE     = 17179869184.0;   // 2^34
constexpr double W_INV_SCALE = 1.0 / 17179869184.0;

typedef int i32x4 __attribute__((ext_vector_type(4)));

// ---------------- fused prep: x -> i8, W -> 4 i8 digit planes ----------------
__global__ __launch_bounds__(256)
void prep_all(const float* __restrict__ x, const float* __restrict__ W,
              signed char* __restrict__ xi8, signed char* __restrict__ pi8)
{
    const int bid = blockIdx.x;
    if (bid < 2048) {
        const int i = bid * 256 + threadIdx.x;           // 16 floats each
        const float4 a = ((const float4*)x)[4 * i + 0];
        const float4 b = ((const float4*)x)[4 * i + 1];
        const float4 c = ((const float4*)x)[4 * i + 2];
        const float4 d = ((const float4*)x)[4 * i + 3];
        const float f[16] = {a.x,a.y,a.z,a.w, b.x,b.y,b.z,b.w,
                             c.x,c.y,c.z,c.w, d.x,d.y,d.z,d.w};
        union { signed char b[16]; int4 v; } u;
#pragma unroll
        for (int j = 0; j < 16; ++j) u.b[j] = (signed char)(f[j] != 0.0f);
        ((int4*)xi8)[i] = u.v;
    } else {
        const int i = (bid - 2048) * 256 + threadIdx.x;  // 4 weights each
        const float4 wv = ((const float4*)W)[i];
        const float wf[4] = {wv.x, wv.y, wv.z, wv.w};
        union { signed char b[4]; unsigned u; } dig[4];
#pragma unroll
        for (int j = 0; j < 4; ++j) {
            int q = __double2int_rn((double)wf[j] * W_SCALE);   // exact rint
            const int d0 = ((q + 128) & 255) - 128;  q = (q - d0) >> 8;
            const int d1 = ((q + 128) & 255) - 128;  q = (q - d1) >> 8;
            const int d2 = ((q + 128) & 255) - 128;  q = (q - d2) >> 8;
            dig[0].b[j] = (signed char)d0;
            dig[1].b[j] = (signed char)d1;
            dig[2].b[j] = (signed char)d2;
            dig[3].b[j] = (signed char)q;                       // |d3| <= ~93
        }
        unsigned* pw = (unsigned*)pi8;
#pragma unroll
        for (int p = 0; p < 4; ++p) pw[p * 262144 + i] = dig[p].u;
    }
}

// ------------- fused exact i8 GEMM + in-block LIF scan, 3 blocks/CU ----------
// Block (bx, by): b = by, o-tile = [bx*64, bx*64+64). M-rows = {t*64+b}.
// 2 staging buffers x 24 KB (A 8K + B 16K) = 48 KB; double-buffer with counted
// vmcnt(3)  [T4 formula: 3 loads/tile/wave x 1 tile in flight -- round 8
// shipped vmcnt(6) here, which never waited for the current tile: race].
// Epilogue curL is a 2-pass overlay (128 x 33 doubles = 33.8 KB <= 48 KB):
// cols 0-31 written+scanned, then cols 32-63. LDS block = 49152 B ->
// 3 blocks/CU (24 waves/CU) for implicit wave-level overlap.
__device__ __forceinline__ void gload_lds16(const signed char* g, signed char* l)
{
    __builtin_amdgcn_global_load_lds(
        (const __attribute__((address_space(1))) unsigned*)(g),
        (__attribute__((address_space(3))) unsigned*)(l), 16, 0, 0);
}

constexpr int BUF_BYTES = 24576;   // A 8192 + B 16384
constexpr int NT_K      = 16;      // 1024 / 64

__global__ __launch_bounds__(512)
void gemm_lif(const signed char* __restrict__ xi8, const signed char* __restrict__ pi8,
              unsigned* __restrict__ outw)
{
    __shared__ __align__(16) unsigned char smem[2 * BUF_BYTES];   // 48 KB
    double (*curL)[33] = (double (*)[33])smem;                    // 33.8 KB overlay

    const int tid  = threadIdx.x;
    const int b    = blockIdx.y;          // batch index, owns all T
    const int o0   = blockIdx.x * 64;     // output-neuron tile
    const int lane = tid & 63;
    const int w    = tid >> 6;            // wave 0..7
    const int wm   = w >> 2;              // 0..1 : t-half
    const int wn   = w & 3;               // 0..3 : o-quarter (16 cols)
    const int l15  = lane & 15;
    const int kg   = lane >> 4;           // 0..3
    const int swzr = (l15 >> 1) & 3;      // read-side chunk XOR

    const int srow   = lane >> 2;                       // 0..15
    const int schunk = (lane & 3) ^ ((lane >> 3) & 3);  // swizzled source chunk

    i32x4 acc[4][4] = {};   // [plane][fm]; D row = kg*4+r (t), col = l15 (o)

    const signed char* gA = xi8 + (size_t)((w * 16 + srow) * 64 + b) * N_IN + schunk * 16;

#define STAGE(KT, BUF)                                                          \
    {                                                                           \
        signed char* As_ = (signed char*)smem + (BUF) * BUF_BYTES;              \
        signed char* Bs_ = As_ + 8192;                                          \
        const int k0_ = (KT) * 64;                                              \
        gload_lds16(gA + k0_, As_ + w * 1024);                                  \
        _Pragma("unroll")                                                       \
        for (int i_ = 0; i_ < 2; ++i_) {                                        \
            const int seg_  = w * 2 + i_;                                       \
            const int p_    = seg_ >> 2;                                        \
            const int rowp_ = (seg_ & 3) * 16 + srow;                           \
            gload_lds16(pi8 + (size_t)p_ * 1048576                              \
                            + (size_t)(o0 + rowp_) * N_IN + k0_ + schunk * 16,  \
                        Bs_ + seg_ * 1024);                                     \
        }                                                                       \
    }

    STAGE(0, 0);

    for (int kt = 0; kt < NT_K; ++kt) {
        const int bufc = kt & 1;
        if (kt < NT_K - 1) {
            STAGE(kt + 1, bufc ^ 1);
            asm volatile("s_waitcnt vmcnt(3)" ::: "memory");   // tile kt landed
        } else {
            asm volatile("s_waitcnt vmcnt(0)" ::: "memory");
        }
        __builtin_amdgcn_s_barrier();   // raw: no compiler vmcnt(0) drain

        const signed char* As = (const signed char*)smem + bufc * BUF_BYTES;
        const signed char* Bs = As + 8192;

        i32x4 af[4], bf[4];
#pragma unroll
        for (int fm = 0; fm < 4; ++fm) {
            const int row = wm * 64 + fm * 16 + l15;     // t within tile
            af[fm] = *(const i32x4*)(As + row * 64 + (kg ^ swzr) * 16);
        }
        {
            const int row = wn * 16 + l15;               // o within tile
#pragma unroll
            for (int p = 0; p < 4; ++p)
                bf[p] = *(const i32x4*)(Bs + p * 4096 + row * 64 + (kg ^ swzr) * 16);
        }

        __builtin_amdgcn_s_setprio(1);
#pragma unroll
        for (int p = 0; p < 4; ++p)
#pragma unroll
            for (int fm = 0; fm < 4; ++fm)
                acc[p][fm] = __builtin_amdgcn_mfma_i32_16x16x64_i8(
                    af[fm], bf[p], acc[p][fm], 0, 0, 0);
        __builtin_amdgcn_s_setprio(0);

        __builtin_amdgcn_s_barrier();   // all waves done reading buf[kt&1]
    }
#undef STAGE

    // ---- epilogue + scan in TWO 32-column passes (curL fits 33.8 KB) ----
    const int onl = wn * 16 + l15;        // o_local 0..63
#pragma unroll
    for (int half = 0; half < 2; ++half) {
        __syncthreads();                  // curL region free (prev pass / main loop)
        if ((wn >> 1) == half) {          // waves owning cols [half*32, half*32+32)
            const int cl = onl - half * 32;
#pragma unroll
            for (int fm = 0; fm < 4; ++fm)
#pragma unroll
                for (int r = 0; r < 4; ++r) {
                    const int t = wm * 64 + fm * 16 + kg * 4 + r;
                    const double q = (double)acc[3][fm][r] * 16777216.0
                                   + (double)acc[2][fm][r] * 65536.0
                                   + (double)acc[1][fm][r] * 256.0
                                   + (double)acc[0][fm][r];
                    curL[t][cl] = q * W_INV_SCALE;
                }
        }
        __syncthreads();
        if (tid < 32) {                   // 32-lane LIF scan over this column half
            const int oc = tid;
            const size_t nbase = (size_t)b * N_OUT + o0 + half * 32 + oc;
            double mem = 0.0;
            double c[8], cn[8];
#pragma unroll
            for (int j = 0; j < 8; ++j) c[j] = curL[j][oc];
            for (int t0 = 0; t0 < T_STEPS; t0 += 8) {
                if (t0 + 8 < T_STEPS) {
#pragma unroll
                    for (int j = 0; j < 8; ++j) cn[j] = curL[t0 + 8 + j][oc];
                }
#pragma unroll
                for (int j = 0; j < 8; ++j) {
                    const double reset = (mem > 1.0) ? 1.0 : 0.0;   // spike of prev mem
                    mem = 0.9 * mem + c[j] - reset;                 // subtract-reset
                    const size_t idx = (size_t)(t0 + j) * NEURONS + nbase;
                    outw[idx]            = (mem > 1.0) ? 0x3f800000u : 0u;  // spk
                    outw[OUT_HALF + idx] = __float_as_uint((float)mem);     // mem
                }
#pragma unroll
                for (int j = 0; j < 8; ++j) c[j] = cn[j];
            }
        }
    }
}

extern "C" void kernel_launch(void* const* d_in, const int* in_sizes, int n_in,
                              void* d_out, int out_size, void* d_ws, size_t ws_size,
                              hipStream_t stream)
{
    const float* x = (const float*)d_in[0];   // (128,64,1024)
    const float* W = (const float*)d_in[1];   // (1024,1024)
    unsigned* outw = (unsigned*)d_out;

    signed char* xi8 = (signed char*)d_ws;                     // 8.39 MB
    signed char* pi8 = xi8 + (size_t)M_TOTAL * N_IN;           // 4 x 1 MB planes

    prep_all<<<3072, 256, 0, stream>>>(x, W, xi8, pi8);

    dim3 ggrid(N_OUT / 64, BATCH);            // 16 x 64 = 1024 blocks
    gemm_lif<<<ggrid, 512, 0, stream>>>(xi8, pi8, outw);
}

// Round 10
// 129.173 us; speedup vs baseline: 1.3372x; 1.3372x over previous
//
#include <hip/hip_runtime.h>
#include <cstddef>

// Problem constants
constexpr int T_STEPS = 128;
constexpr int BATCH   = 64;
constexpr int N_IN    = 1024;
constexpr int N_OUT   = 1024;
constexpr int M_TOTAL = T_STEPS * BATCH;     // 8192 GEMM rows (m = t*64 + b)
constexpr int NEURONS = BATCH * N_OUT;       // 65536
constexpr int OUT_HALF = T_STEPS * NEURONS;  // 8388608 floats per output tensor

// Exact-arithmetic scheme (unchanged): q = rint(W * 2^34), 4 balanced radix-256
// i8 digits; i32 MFMA accumulation exact; fp64 recombine exact (< 2^42);
// cur = q_sum * 2^-34 exact. Bit-identical outputs vs rounds 3-7.
constexpr double W_SCALE     = 17179869184.0;   // 2^34
constexpr double W_INV_SCALE = 1.0 / 17179869184.0;

typedef int i32x4 __attribute__((ext_vector_type(4)));

// ---------------- fused prep: x -> i8, W -> 4 i8 digit planes ----------------
__global__ __launch_bounds__(256)
void prep_all(const float* __restrict__ x, const float* __restrict__ W,
              signed char* __restrict__ xi8, signed char* __restrict__ pi8)
{
    const int bid = blockIdx.x;
    if (bid < 2048) {
        const int i = bid * 256 + threadIdx.x;           // 16 floats each
        const float4 a = ((const float4*)x)[4 * i + 0];
        const float4 b = ((const float4*)x)[4 * i + 1];
        const float4 c = ((const float4*)x)[4 * i + 2];
        const float4 d = ((const float4*)x)[4 * i + 3];
        const float f[16] = {a.x,a.y,a.z,a.w, b.x,b.y,b.z,b.w,
                             c.x,c.y,c.z,c.w, d.x,d.y,d.z,d.w};
        union { signed char b[16]; int4 v; } u;
#pragma unroll
        for (int j = 0; j < 16; ++j) u.b[j] = (signed char)(f[j] != 0.0f);
        ((int4*)xi8)[i] = u.v;
    } else {
        const int i = (bid - 2048) * 256 + threadIdx.x;  // 4 weights each
        const float4 wv = ((const float4*)W)[i];
        const float wf[4] = {wv.x, wv.y, wv.z, wv.w};
        union { signed char b[4]; unsigned u; } dig[4];
#pragma unroll
        for (int j = 0; j < 4; ++j) {
            int q = __double2int_rn((double)wf[j] * W_SCALE);   // exact rint
            const int d0 = ((q + 128) & 255) - 128;  q = (q - d0) >> 8;
            const int d1 = ((q + 128) & 255) - 128;  q = (q - d1) >> 8;
            const int d2 = ((q + 128) & 255) - 128;  q = (q - d2) >> 8;
            dig[0].b[j] = (signed char)d0;
            dig[1].b[j] = (signed char)d1;
            dig[2].b[j] = (signed char)d2;
            dig[3].b[j] = (signed char)q;                       // |d3| <= ~93
        }
        unsigned* pw = (unsigned*)pi8;
#pragma unroll
        for (int p = 0; p < 4; ++p) pw[p * 262144 + i] = dig[p].u;
    }
}

// ------------- fused exact i8 GEMM + in-block LIF scan (round-7 config) ------
// Block (bx, by): b = by, o-tile = [bx*64, bx*64+64). M-rows = {t*64+b}.
// 3 staging buffers x 24 KB, gload_lds w16, XOR chunk swizzle (0 conflicts),
// depth-2 prefetch with counted vmcnt(6) [T4: 3 loads/tile x 2 tiles in
// flight]. Residency: 60 VGPR + 64 AGPR = 124 regs -> 4 waves/SIMD ->
// 2 blocks/CU (this is the structural ceiling for t-complete fused blocks:
// acc = 512/W regs for W waves; launch_bounds(512,4) pins it).
__device__ __forceinline__ void gload_lds16(const signed char* g, signed char* l)
{
    __builtin_amdgcn_global_load_lds(
        (const __attribute__((address_space(1))) unsigned*)(g),
        (__attribute__((address_space(3))) unsigned*)(l), 16, 0, 0);
}

constexpr int BUF_BYTES = 24576;   // A 8192 + B 16384
constexpr int NT_K      = 16;      // 1024 / 64

__global__ __launch_bounds__(512, 4)
void gemm_lif(const signed char* __restrict__ xi8, const signed char* __restrict__ pi8,
              unsigned* __restrict__ outw)
{
    __shared__ __align__(16) unsigned char smem[3 * BUF_BYTES];   // 72 KB
    double (*curL)[66] = (double (*)[66])smem;                    // 67.6 KB overlay

    const int tid  = threadIdx.x;
    const int b    = blockIdx.y;          // batch index, owns all T
    const int o0   = blockIdx.x * 64;     // output-neuron tile
    const int lane = tid & 63;
    const int w    = tid >> 6;            // wave 0..7
    const int wm   = w >> 2;              // 0..1 : t-half
    const int wn   = w & 3;               // 0..3 : o-quarter (16 cols)
    const int l15  = lane & 15;
    const int kg   = lane >> 4;           // 0..3
    const int swzr = (l15 >> 1) & 3;      // read-side chunk XOR

    const int srow   = lane >> 2;                       // 0..15
    const int schunk = (lane & 3) ^ ((lane >> 3) & 3);  // swizzled source chunk

    i32x4 acc[4][4] = {};   // [plane][fm]; D row = kg*4+r (t), col = l15 (o)

    const signed char* gA = xi8 + (size_t)((w * 16 + srow) * 64 + b) * N_IN + schunk * 16;

#define STAGE(KT, BUF)                                                          \
    {                                                                           \
        signed char* As_ = (signed char*)smem + (BUF) * BUF_BYTES;              \
        signed char* Bs_ = As_ + 8192;                                          \
        const int k0_ = (KT) * 64;                                              \
        gload_lds16(gA + k0_, As_ + w * 1024);                                  \
        _Pragma("unroll")                                                       \
        for (int i_ = 0; i_ < 2; ++i_) {                                        \
            const int seg_  = w * 2 + i_;                                       \
            const int p_    = seg_ >> 2;                                        \
            const int rowp_ = (seg_ & 3) * 16 + srow;                           \
            gload_lds16(pi8 + (size_t)p_ * 1048576                              \
                            + (size_t)(o0 + rowp_) * N_IN + k0_ + schunk * 16,  \
                        Bs_ + seg_ * 1024);                                     \
        }                                                                       \
    }

    STAGE(0, 0);
    STAGE(1, 1);

    for (int kt = 0; kt < NT_K; ++kt) {
        const int bufc = kt % 3;
        if (kt < NT_K - 2) {
            STAGE(kt + 2, (kt + 2) % 3);
            asm volatile("s_waitcnt vmcnt(6)" ::: "memory");   // tile kt landed
        } else if (kt == NT_K - 2) {
            asm volatile("s_waitcnt vmcnt(3)" ::: "memory");
        } else {
            asm volatile("s_waitcnt vmcnt(0)" ::: "memory");
        }
        __builtin_amdgcn_s_barrier();   // raw: no compiler vmcnt(0) drain

        const signed char* As = (const signed char*)smem + bufc * BUF_BYTES;
        const signed char* Bs = As + 8192;

        i32x4 af[4], bf[4];
#pragma unroll
        for (int fm = 0; fm < 4; ++fm) {
            const int row = wm * 64 + fm * 16 + l15;     // t within tile
            af[fm] = *(const i32x4*)(As + row * 64 + (kg ^ swzr) * 16);
        }
        {
            const int row = wn * 16 + l15;               // o within tile
#pragma unroll
            for (int p = 0; p < 4; ++p)
                bf[p] = *(const i32x4*)(Bs + p * 4096 + row * 64 + (kg ^ swzr) * 16);
        }

        __builtin_amdgcn_s_setprio(1);
#pragma unroll
        for (int p = 0; p < 4; ++p)
#pragma unroll
            for (int fm = 0; fm < 4; ++fm)
                acc[p][fm] = __builtin_amdgcn_mfma_i32_16x16x64_i8(
                    af[fm], bf[p], acc[p][fm], 0, 0, 0);
        __builtin_amdgcn_s_setprio(0);

        __builtin_amdgcn_s_barrier();   // all waves done reading buf[kt%3]
    }
#undef STAGE

    // ---- epilogue: exact fp64 recombine into LDS curL[t][o_local] ----
    const int onl = wn * 16 + l15;        // o_local 0..63
#pragma unroll
    for (int fm = 0; fm < 4; ++fm)
#pragma unroll
        for (int r = 0; r < 4; ++r) {
            const int t = wm * 64 + fm * 16 + kg * 4 + r;
            const double q = (double)acc[3][fm][r] * 16777216.0
                           + (double)acc[2][fm][r] * 65536.0
                           + (double)acc[1][fm][r] * 256.0
                           + (double)acc[0][fm][r];
            curL[t][onl] = q * W_INV_SCALE;
        }
    __syncthreads();

    // ---- in-block LIF scan: 64 lanes of wave 0, one neuron each ----
    if (tid < 64) {
        const int oc = tid;
        const size_t nbase = (size_t)b * N_OUT + o0 + oc;
        double mem = 0.0;
        double c[8], cn[8];
#pragma unroll
        for (int j = 0; j < 8; ++j) c[j] = curL[j][oc];
        for (int t0 = 0; t0 < T_STEPS; t0 += 8) {
            if (t0 + 8 < T_STEPS) {
#pragma unroll
                for (int j = 0; j < 8; ++j) cn[j] = curL[t0 + 8 + j][oc];
            }
#pragma unroll
            for (int j = 0; j < 8; ++j) {
                const double reset = (mem > 1.0) ? 1.0 : 0.0;   // spike of prev mem
                mem = 0.9 * mem + c[j] - reset;                 // subtract-reset, thr=1
                const size_t idx = (size_t)(t0 + j) * NEURONS + nbase;
                outw[idx]            = (mem > 1.0) ? 0x3f800000u : 0u;  // spk bits
                outw[OUT_HALF + idx] = __float_as_uint((float)mem);     // mem fp32
            }
#pragma unroll
            for (int j = 0; j < 8; ++j) c[j] = cn[j];
        }
    }
}

extern "C" void kernel_launch(void* const* d_in, const int* in_sizes, int n_in,
                              void* d_out, int out_size, void* d_ws, size_t ws_size,
                              hipStream_t stream)
{
    const float* x = (const float*)d_in[0];   // (128,64,1024)
    const float* W = (const float*)d_in[1];   // (1024,1024)
    unsigned* outw = (unsigned*)d_out;

    signed char* xi8 = (signed char*)d_ws;                     // 8.39 MB
    signed char* pi8 = xi8 + (size_t)M_TOTAL * N_IN;           // 4 x 1 MB planes

    prep_all<<<3072, 256, 0, stream>>>(x, W, xi8, pi8);

    dim3 ggrid(N_OUT / 64, BATCH);            // 16 x 64 = 1024 blocks
    gemm_lif<<<ggrid, 512, 0, stream>>>(xi8, pi8, outw);
}